// Round 10
// baseline (96.397 us; speedup 1.0000x reference)
//
#include <hip/hip_runtime.h>

// MMD loss, N=4096 per side, D=256, fp32.
// R26: dispatch-boundary collapse (4 -> 2). R25 measured: async-stage
//      persistent pipeline bought only 1.2 us (96.3) -- wave-level TLP had
//      already captured the overlap (m99/m100 lesson). k_pairs ~28 us vs
//      ~14-19 floor has resisted 7 structural attacks; the OTHER line item:
//      each dispatch boundary costs ~3.3 us (consistent R16/R21/R25) and
//      k_scale/k_fin are overhead shells (~12 us total incl. gaps).
//      Merge both into k_pairs:
//        - scale computed per-block in the prologue (bit-identical op order
//          to old k_scale; deterministic -> same value in every block),
//          overlapped with first-tile DMA; part 256KB L2-caches per XCD.
//        - final reduce: block partial atomicAdd'ed to 8 spread slots;
//          counter bump DATA-DEPENDENT on the atomic return (R17-proven
//          ordering, NO __threadfence); block seeing prev==511 atomically
//          reads slots and plain-stores out[0]. Zeroing moved to k_conv
//          block 0 (prior dispatch -> visible).
//      Tile loop / staging / packed epilogue BYTE-FROZEN from R25.
//      Lessons: NO __threadfence (R8-R10), NO cooperative (R17), unrolled
//      indices only (R8/R9), occupancy/bytes/atomics/delivery not the lever
//      (R18-R21), ablate don't guess (R22), packed epilogue (R24).

#define NROWS 8192
#define HALF  4096
#define DIM   256
#define CONVB 256
#define NTILE 2080        // 128x128 tiles: 64*65/2, J>=I
#define GRIDP 512         // persistent k_pairs blocks, all co-resident

typedef float f32x4 __attribute__((ext_vector_type(4)));
typedef float f32x2 __attribute__((ext_vector_type(2)));

__device__ __forceinline__ const float* row_ptr(const float* src, const float* tgt, int r) {
    return (r < HALF) ? (src + (size_t)r * DIM) : (tgt + (size_t)(r - HALF) * DIM);
}

__device__ __forceinline__ void gload_lds16(const void* g, void* l) {
    __builtin_amdgcn_global_load_lds(
        (const __attribute__((address_space(1))) unsigned int*)g,
        (__attribute__((address_space(3))) unsigned int*)l, 16, 0, 0);
}

// Stage one 128-row fp8 panel (32 KB) into lds; 32 DMA instrs, wave w takes
// k%4==w. Source row pre-swizzled rg = r ^ ((u&3)<<1); LDS linear.
__device__ __forceinline__ void stage_panel(const ulonglong2* plane, int P,
                                            ulonglong2* lds, int w, int lane) {
    #pragma unroll
    for (int i = 0; i < 8; ++i) {
        int k = w + 4 * i;                  // 0..31, wave-uniform split
        int u = k >> 1;
        int h = k & 1;
        int rg = (h * 64 + lane) ^ ((u & 3) << 1);
        gload_lds16(plane + (size_t)P * 2048 + (size_t)u * 128 + rg,
                    lds + u * 128 + h * 64);
    }
}

// --- Phase 0: fp32 -> fp8 plane (tiled, k-interleaved) + sq/colsum/S1 ---
__global__ __launch_bounds__(256) void k_conv(const float* __restrict__ src,
                                              const float* __restrict__ tgt,
                                              unsigned char* __restrict__ hi,
                                              float* __restrict__ sq,
                                              float* __restrict__ part,
                                              double* __restrict__ parts1,
                                              float* __restrict__ outacc,
                                              unsigned int* __restrict__ cnt,
                                              float* __restrict__ out) {
    __shared__ __align__(16) unsigned char sh8[32 * 256];  // 8 KB, octet-swizzled
    __shared__ float4 cs[4][64];
    __shared__ double s1s[4];

    int w = threadIdx.x >> 6, lane = threadIdx.x & 63;
    int r0 = blockIdx.x * 32;

    float4 v[8];
    #pragma unroll
    for (int i = 0; i < 8; ++i) {
        int row = r0 + w * 8 + i;
        v[i] = ((const float4*)row_ptr(src, tgt, row))[lane];
    }

    // Zero the R26 cross-dispatch accumulators (ws poisoned 0xAA each iter).
    if (blockIdx.x == 0) {
        if (threadIdx.x < 8) outacc[threadIdx.x] = 0.0f;
        if (threadIdx.x == 0) { *cnt = 0u; out[0] = 0.0f; }
    }

    float4 csum = {0.f, 0.f, 0.f, 0.f};
    double s1w = 0.0;
    #pragma unroll
    for (int i = 0; i < 8; ++i) {
        int rl  = w * 8 + i;
        float xs[4] = {v[i].x, v[i].y, v[i].z, v[i].w};
        int pk = __builtin_amdgcn_cvt_pk_fp8_f32(xs[0], xs[1], 0, false);
        pk     = __builtin_amdgcn_cvt_pk_fp8_f32(xs[2], xs[3], pk, true);
        int o  = lane >> 1, h = lane & 1;
        *(int*)&sh8[rl * 256 + (((o ^ rl) & 31) << 3) + (h << 2)] = pk;
        csum.x += xs[0]; csum.y += xs[1]; csum.z += xs[2]; csum.w += xs[3];
        float sf = xs[0]*xs[0] + xs[1]*xs[1] + xs[2]*xs[2] + xs[3]*xs[3];
        float q0 = __builtin_amdgcn_cvt_f32_fp8(pk, 0);
        float q1 = __builtin_amdgcn_cvt_f32_fp8(pk, 1);
        float q2 = __builtin_amdgcn_cvt_f32_fp8(pk, 2);
        float q3 = __builtin_amdgcn_cvt_f32_fp8(pk, 3);
        float sQ = q0*q0 + q1*q1 + q2*q2 + q3*q3;
        #pragma unroll
        for (int off = 32; off; off >>= 1) {
            sf += __shfl_xor(sf, off, 64);
            sQ += __shfl_xor(sQ, off, 64);
        }
        if (lane == 0) { sq[r0 + rl] = sQ; s1w += (double)sf; }
    }
    __syncthreads();
    int panel = blockIdx.x >> 2, quarter = blockIdx.x & 3;
    #pragma unroll
    for (int c = threadIdx.x; c < 512; c += 256) {
        int u = c >> 5, rl = c & 31;
        int tt = u >> 2, j = u & 3;
        int o0 = 8 * tt + j;
        int o1 = 8 * tt + 4 + j;
        unsigned long long q0 = *(const unsigned long long*)
            &sh8[rl * 256 + (((o0 ^ rl) & 31) << 3)];
        unsigned long long q1 = *(const unsigned long long*)
            &sh8[rl * 256 + (((o1 ^ rl) & 31) << 3)];
        ulonglong2 q = {q0, q1};
        size_t goff = ((size_t)panel * 2048 + (size_t)u * 128 + quarter * 32 + rl);
        ((ulonglong2*)hi)[goff] = q;
    }
    cs[w][lane] = csum;
    if (lane == 0) s1s[w] = s1w;
    __syncthreads();
    if (w == 0) {
        float4 a = cs[0][lane], b = cs[1][lane], c = cs[2][lane], d = cs[3][lane];
        float4 tot = {a.x + b.x + c.x + d.x, a.y + b.y + c.y + d.y,
                      a.z + b.z + c.z + d.z, a.w + b.w + c.w + d.w};
        *(float4*)&part[(size_t)blockIdx.x * DIM + lane * 4] = tot;
        if (lane == 0) parts1[blockIdx.x] = s1s[0] + s1s[1] + s1s[2] + s1s[3];
    }
}

// --- Phase 1+2+3 fused: persistent pipelined fp8 MFMA pair kernel ---
// Prologue computes scale per-block (bit-identical to old k_scale) under
// the first-tile DMA; tail does spread-atomic + counter final reduce.
__global__ __launch_bounds__(256, 2) void k_pairs(const unsigned char* __restrict__ hi,
                                                  const float* __restrict__ sq,
                                                  const float* __restrict__ part,
                                                  const double* __restrict__ parts1,
                                                  float* __restrict__ outacc,
                                                  unsigned int* __restrict__ cnt,
                                                  float* __restrict__ out) {
    __shared__ __align__(16) ulonglong2 ldsA[2048];   // 32 KB: panel I
    __shared__ __align__(16) ulonglong2 ldsB[2048];   // 32 KB: panel J
    __shared__ float wsum[4];
    __shared__ double shd[256];                        // scale reduction

    int bid = blockIdx.x;
    int t0 = (bid * NTILE) / GRIDP;
    int t1 = ((bid + 1) * NTILE) / GRIDP;

    // Decode start tile t0 -> (I, J) in I-major triangle order.
    int id = t0, I = 0;
    for (;;) {
        int c = 64 - I;
        if (id < c) break;
        id -= c; ++I;
    }
    int J = I + id;

    int t    = threadIdx.x;
    int lane = t & 63;
    int w    = t >> 6;
    int lr   = lane & 15, lq = lane >> 4;
    int wr   = w >> 1, wc = w & 1;
    int lrx  = lr ^ (lq << 1);

    const ulonglong2* plane = (const ulonglong2*)hi;

    // Prologue: issue first tile's staging DMA, then compute scale under it.
    stage_panel(plane, I, ldsA, w, lane);
    if (J != I) stage_panel(plane, J, ldsB, w, lane);

    // ---- in-prologue scale compute (former k_scale, op-order identical) ----
    shd[t] = parts1[t];
    __syncthreads();
    for (int off = 128; off; off >>= 1) {
        if (t < off) shd[t] += shd[t + off];
        __syncthreads();
    }
    double S1 = shd[0];
    __syncthreads();
    {
        float c0 = 0.f, c1 = 0.f, c2 = 0.f, c3 = 0.f;
        #pragma unroll 16
        for (int b = 0; b < CONVB; b += 4) {
            c0 += part[(b + 0) * DIM + t];
            c1 += part[(b + 1) * DIM + t];
            c2 += part[(b + 2) * DIM + t];
            c3 += part[(b + 3) * DIM + t];
        }
        double c = (double)((c0 + c1) + (c2 + c3));
        shd[t] = c * c;
    }
    __syncthreads();
    for (int off = 128; off; off >>= 1) {
        if (t < off) shd[t] += shd[t + off];
        __syncthreads();
    }
    double S2    = shd[0];
    double nd    = (double)NROWS;
    double sumL2 = 2.0 * nd * S1 - 2.0 * S2;
    double bw    = sumL2 / (nd * nd - nd) / 4.0;   // / KERNEL_MUL^(KERNEL_NUM//2)
    float  s     = (float)(-1.0 / (16.0 * bw * 0.69314718055994530942));
    f32x2  m2s   = {-2.0f * s, -2.0f * s};

    asm volatile("s_waitcnt vmcnt(0)");
    __syncthreads();

    float wtot = 0.0f;
    int curI = I, curJ = J;

    #pragma unroll 1
    for (int tile = t0; tile < t1; ++tile) {
        const ulonglong2* lB  = (curJ == curI) ? ldsA : ldsB;
        const ulonglong2* pAl = ldsA + lq * 128 + wr * 64 + lrx;
        const ulonglong2* pBl = lB   + lq * 128 + wc * 64 + lrx;

        // Hoist ALL 32 fragment reads to registers (frees LDS for prefetch).
        ulonglong2 fA[4][4], fB[4][4];
        #pragma unroll
        for (int tt = 0; tt < 4; ++tt) {
            #pragma unroll
            for (int m = 0; m < 4; ++m) fA[tt][m] = pAl[tt * 512 + m * 16];
            #pragma unroll
            for (int n = 0; n < 4; ++n) fB[tt][n] = pBl[tt * 512 + n * 16];
        }
        __syncthreads();   // all waves' LDS reads retired (lgkmcnt auto)

        // Issue NEXT tile's DMA now; it fills LDS under the MFMA+epilogue.
        int nI = curI, nJ = curJ + 1;
        if (nJ == 64) { nI = curI + 1; nJ = nI; }
        if (tile + 1 < t1) {
            if (nI != curI) stage_panel(plane, nI, ldsA, w, lane);  // diag next: B aliases A
            else            stage_panel(plane, nJ, ldsB, w, lane);  // same-I run: B only
        }

        // MFMA from registers.
        f32x4 acc[4][4];
        #pragma unroll
        for (int m = 0; m < 4; ++m)
            #pragma unroll
            for (int n = 0; n < 4; ++n) acc[m][n] = (f32x4){0.f, 0.f, 0.f, 0.f};
        #pragma unroll
        for (int tt = 0; tt < 4; ++tt) {
            #pragma unroll
            for (int m = 0; m < 4; ++m)
                #pragma unroll
                for (int n = 0; n < 4; ++n)
                    acc[m][n] = __builtin_amdgcn_mfma_f32_16x16x32_fp8_fp8(
                        (long)fA[tt][m].x, (long)fB[tt][n].x, acc[m][n], 0, 0, 0);
            #pragma unroll
            for (int m = 0; m < 4; ++m)
                #pragma unroll
                for (int n = 0; n < 4; ++n)
                    acc[m][n] = __builtin_amdgcn_mfma_f32_16x16x32_fp8_fp8(
                        (long)fA[tt][m].y, (long)fB[tt][n].y, acc[m][n], 0, 0, 0);
        }

        // Packed epilogue (frozen R24 math), per-tile weight/sign folded in.
        float wgt = (curJ == curI) ? 1.0f : 2.0f;
        float sgn = ((curI < 32) == (curJ < 32)) ? 1.0f : -1.0f;
        int ro_eff = curI * 128 + wr * 64;
        int co_eff = curJ * 128 + wc * 64;
        float4 sqa4[4];
        float  sqbv[4];
        #pragma unroll
        for (int m = 0; m < 4; ++m) sqa4[m] = *(const float4*)&sq[ro_eff + m * 16 + lq * 4];
        #pragma unroll
        for (int n = 0; n < 4; ++n) sqbv[n] = s * sq[co_eff + n * 16 + lr];

        f32x2 ssa01[4], ssa23[4];
        #pragma unroll
        for (int m = 0; m < 4; ++m) {
            ssa01[m] = (f32x2){s * sqa4[m].x, s * sqa4[m].y};
            ssa23[m] = (f32x2){s * sqa4[m].z, s * sqa4[m].w};
        }

        f32x2 acc0 = {0.f, 0.f}, acc1 = {0.f, 0.f};
        #pragma unroll
        for (int m = 0; m < 4; ++m) {
            #pragma unroll
            for (int n = 0; n < 4; ++n) {
                f32x2 sbn = {sqbv[n], sqbv[n]};
                f32x2 a01 = {acc[m][n][0], acc[m][n][1]};
                f32x2 a23 = {acc[m][n][2], acc[m][n][3]};
                f32x2 e01 = (ssa01[m] + sbn) + m2s * a01;
                f32x2 e23 = (ssa23[m] + sbn) + m2s * a23;
                f32x2 u01, u23;
                u01.x = __builtin_amdgcn_exp2f(e01.x);
                u01.y = __builtin_amdgcn_exp2f(e01.y);
                u23.x = __builtin_amdgcn_exp2f(e23.x);
                u23.y = __builtin_amdgcn_exp2f(e23.y);
                f32x2 p2a = u01 * u01, p4a = p2a * p2a, p8a = p4a * p4a, p16a = p8a * p8a;
                f32x2 p2b = u23 * u23, p4b = p2b * p2b, p8b = p4b * p4b, p16b = p8b * p8b;
                acc0 += ((u01 + p2a) + (p4a + p8a)) + p16a;
                acc1 += ((u23 + p2b) + (p4b + p8b)) + p16b;
            }
        }
        wtot += ((acc0.x + acc0.y) + (acc1.x + acc1.y)) * sgn * wgt;

        // DMA for next tile must be complete before next iter's LDS reads.
        asm volatile("s_waitcnt vmcnt(0)");
        __syncthreads();
        curI = nI; curJ = nJ;
    }

    #pragma unroll
    for (int off = 32; off; off >>= 1) wtot += __shfl_xor(wtot, off, 64);
    if (lane == 0) wsum[w] = wtot;
    __syncthreads();
    if (t == 0) {
        float tot = (wsum[0] + wsum[1] + wsum[2] + wsum[3])
                  * (1.0f / ((float)HALF * (float)HALF));
        // Spread-slot atomic partial (device coherent point).
        float r = atomicAdd(&outacc[bid & 7], tot);
        // Counter bump made data-dependent on the RETURNED atomic -> the
        // partial is globally committed before the counter increments
        // (R17-proven ordering; no __threadfence).
        asm volatile("" :: "v"(r) : "memory");
        unsigned prev = atomicAdd(cnt, 1u);
        if (prev == (unsigned)(GRIDP - 1)) {
            float total = 0.0f;
            #pragma unroll
            for (int k2 = 0; k2 < 8; ++k2) total += atomicAdd(&outacc[k2], 0.0f);
            out[0] = total;
        }
    }
}

extern "C" void kernel_launch(void* const* d_in, const int* in_sizes, int n_in,
                              void* d_out, int out_size, void* d_ws, size_t ws_size,
                              hipStream_t stream) {
    const float* src = (const float*)d_in[0];
    const float* tgt = (const float*)d_in[1];
    float* out = (float*)d_out;

    char* ws = (char*)d_ws;
    unsigned int* cnt = (unsigned int*)(ws + 0);                 // 4 B
    float*  outacc = (float*)(ws + 64);                          // 32 B
    float*  sq     = (float*)(ws + 128);                         // 32768 B
    float*  part   = (float*)(ws + 33024);                       // 256*256*4 B
    double* parts1 = (double*)(ws + 295424);                     // 256*8 B
    unsigned char* hi = (unsigned char*)(ws + 297472);           // 2 MB, 16B-aligned

    k_conv <<<CONVB, 256, 0, stream>>>(src, tgt, hi, sq, part, parts1,
                                       outacc, cnt, out);
    k_pairs<<<GRIDP, 256, 0, stream>>>(hi, sq, part, parts1, outacc, cnt, out);
}

// Round 11
// 95.960 us; speedup vs baseline: 1.0046x; 1.0046x over previous
//
#include <hip/hip_runtime.h>

// MMD loss, N=4096 per side, D=256, fp32.
// R27: cross-tile MFMA||VALU interleave inside k_pairs. R26 measured: the
//      4->2 dispatch collapse = ZERO (96.4 vs 96.3) -> boundary model dead;
//      all inter-phase structure exhausted. R22 probe arithmetic: 8150
//      cyc/wave-tile vs ~2600-3300 issue-accounted; MfmaUtil 25 + VALU 49
//      -> ~26% no-issue stall; per-wave serial chain reads->lgkm->MFMA->
//      epilogue in phase-locked blocks = MFMA idle under epilogue & vice
//      versa. Fix (one lever): two accumulators. Per tt-group (unrolled):
//      {8 ds_reads(cur) -> epilogue-chunk tt of PREV tile (register-only
//      VALU, fills the lgkm shadow) -> 32 MFMA(cur)}. MFMA(cur) overlaps
//      epilogue(prev); first tile MFMA-only; last epilogue after loop;
//      accA<-accB unrolled copy (static names, rule #20). VGPR ~205 ->
//      2 blk/CU kept. Scale prologue / staging / atomic tail / k_conv
//      BYTE-FROZEN from R26.
//      Lessons: NO __threadfence (R8-R10), NO cooperative (R17), unrolled
//      indices only (R8/R9), occupancy/bytes/atomics/boundaries not the
//      lever (R18-R21,R26), ablate don't guess (R22), packed epilogue (R24).

#define NROWS 8192
#define HALF  4096
#define DIM   256
#define CONVB 256
#define NTILE 2080        // 128x128 tiles: 64*65/2, J>=I
#define GRIDP 512         // persistent k_pairs blocks, all co-resident

typedef float f32x4 __attribute__((ext_vector_type(4)));
typedef float f32x2 __attribute__((ext_vector_type(2)));

__device__ __forceinline__ const float* row_ptr(const float* src, const float* tgt, int r) {
    return (r < HALF) ? (src + (size_t)r * DIM) : (tgt + (size_t)(r - HALF) * DIM);
}

__device__ __forceinline__ void gload_lds16(const void* g, void* l) {
    __builtin_amdgcn_global_load_lds(
        (const __attribute__((address_space(1))) unsigned int*)g,
        (__attribute__((address_space(3))) unsigned int*)l, 16, 0, 0);
}

// Stage one 128-row fp8 panel (32 KB) into lds; 32 DMA instrs, wave w takes
// k%4==w. Source row pre-swizzled rg = r ^ ((u&3)<<1); LDS linear.
__device__ __forceinline__ void stage_panel(const ulonglong2* plane, int P,
                                            ulonglong2* lds, int w, int lane) {
    #pragma unroll
    for (int i = 0; i < 8; ++i) {
        int k = w + 4 * i;                  // 0..31, wave-uniform split
        int u = k >> 1;
        int h = k & 1;
        int rg = (h * 64 + lane) ^ ((u & 3) << 1);
        gload_lds16(plane + (size_t)P * 2048 + (size_t)u * 128 + rg,
                    lds + u * 128 + h * 64);
    }
}

// --- Phase 0: fp32 -> fp8 plane (tiled, k-interleaved) + sq/colsum/S1 ---
__global__ __launch_bounds__(256) void k_conv(const float* __restrict__ src,
                                              const float* __restrict__ tgt,
                                              unsigned char* __restrict__ hi,
                                              float* __restrict__ sq,
                                              float* __restrict__ part,
                                              double* __restrict__ parts1,
                                              float* __restrict__ outacc,
                                              unsigned int* __restrict__ cnt,
                                              float* __restrict__ out) {
    __shared__ __align__(16) unsigned char sh8[32 * 256];  // 8 KB, octet-swizzled
    __shared__ float4 cs[4][64];
    __shared__ double s1s[4];

    int w = threadIdx.x >> 6, lane = threadIdx.x & 63;
    int r0 = blockIdx.x * 32;

    float4 v[8];
    #pragma unroll
    for (int i = 0; i < 8; ++i) {
        int row = r0 + w * 8 + i;
        v[i] = ((const float4*)row_ptr(src, tgt, row))[lane];
    }

    // Zero cross-dispatch accumulators (ws poisoned 0xAA each iteration).
    if (blockIdx.x == 0) {
        if (threadIdx.x < 8) outacc[threadIdx.x] = 0.0f;
        if (threadIdx.x == 0) { *cnt = 0u; out[0] = 0.0f; }
    }

    float4 csum = {0.f, 0.f, 0.f, 0.f};
    double s1w = 0.0;
    #pragma unroll
    for (int i = 0; i < 8; ++i) {
        int rl  = w * 8 + i;
        float xs[4] = {v[i].x, v[i].y, v[i].z, v[i].w};
        int pk = __builtin_amdgcn_cvt_pk_fp8_f32(xs[0], xs[1], 0, false);
        pk     = __builtin_amdgcn_cvt_pk_fp8_f32(xs[2], xs[3], pk, true);
        int o  = lane >> 1, h = lane & 1;
        *(int*)&sh8[rl * 256 + (((o ^ rl) & 31) << 3) + (h << 2)] = pk;
        csum.x += xs[0]; csum.y += xs[1]; csum.z += xs[2]; csum.w += xs[3];
        float sf = xs[0]*xs[0] + xs[1]*xs[1] + xs[2]*xs[2] + xs[3]*xs[3];
        float q0 = __builtin_amdgcn_cvt_f32_fp8(pk, 0);
        float q1 = __builtin_amdgcn_cvt_f32_fp8(pk, 1);
        float q2 = __builtin_amdgcn_cvt_f32_fp8(pk, 2);
        float q3 = __builtin_amdgcn_cvt_f32_fp8(pk, 3);
        float sQ = q0*q0 + q1*q1 + q2*q2 + q3*q3;
        #pragma unroll
        for (int off = 32; off; off >>= 1) {
            sf += __shfl_xor(sf, off, 64);
            sQ += __shfl_xor(sQ, off, 64);
        }
        if (lane == 0) { sq[r0 + rl] = sQ; s1w += (double)sf; }
    }
    __syncthreads();
    int panel = blockIdx.x >> 2, quarter = blockIdx.x & 3;
    #pragma unroll
    for (int c = threadIdx.x; c < 512; c += 256) {
        int u = c >> 5, rl = c & 31;
        int tt = u >> 2, j = u & 3;
        int o0 = 8 * tt + j;
        int o1 = 8 * tt + 4 + j;
        unsigned long long q0 = *(const unsigned long long*)
            &sh8[rl * 256 + (((o0 ^ rl) & 31) << 3)];
        unsigned long long q1 = *(const unsigned long long*)
            &sh8[rl * 256 + (((o1 ^ rl) & 31) << 3)];
        ulonglong2 q = {q0, q1};
        size_t goff = ((size_t)panel * 2048 + (size_t)u * 128 + quarter * 32 + rl);
        ((ulonglong2*)hi)[goff] = q;
    }
    cs[w][lane] = csum;
    if (lane == 0) s1s[w] = s1w;
    __syncthreads();
    if (w == 0) {
        float4 a = cs[0][lane], b = cs[1][lane], c = cs[2][lane], d = cs[3][lane];
        float4 tot = {a.x + b.x + c.x + d.x, a.y + b.y + c.y + d.y,
                      a.z + b.z + c.z + d.z, a.w + b.w + c.w + d.w};
        *(float4*)&part[(size_t)blockIdx.x * DIM + lane * 4] = tot;
        if (lane == 0) parts1[blockIdx.x] = s1s[0] + s1s[1] + s1s[2] + s1s[3];
    }
}

// --- fused persistent k_pairs: scale prologue + pipelined tiles + tail ---
__global__ __launch_bounds__(256, 2) void k_pairs(const unsigned char* __restrict__ hi,
                                                  const float* __restrict__ sq,
                                                  const float* __restrict__ part,
                                                  const double* __restrict__ parts1,
                                                  float* __restrict__ outacc,
                                                  unsigned int* __restrict__ cnt,
                                                  float* __restrict__ out) {
    __shared__ __align__(16) ulonglong2 ldsA[2048];   // 32 KB: panel I
    __shared__ __align__(16) ulonglong2 ldsB[2048];   // 32 KB: panel J
    __shared__ float wsum[4];
    __shared__ double shd[256];                        // scale reduction

    int bid = blockIdx.x;
    int t0 = (bid * NTILE) / GRIDP;
    int t1 = ((bid + 1) * NTILE) / GRIDP;

    // Decode start tile t0 -> (I, J) in I-major triangle order.
    int id = t0, I = 0;
    for (;;) {
        int c = 64 - I;
        if (id < c) break;
        id -= c; ++I;
    }
    int J = I + id;

    int t    = threadIdx.x;
    int lane = t & 63;
    int w    = t >> 6;
    int lr   = lane & 15, lq = lane >> 4;
    int wr   = w >> 1, wc = w & 1;
    int lrx  = lr ^ (lq << 1);

    const ulonglong2* plane = (const ulonglong2*)hi;

    // Prologue: issue first tile's staging DMA, then compute scale under it.
    stage_panel(plane, I, ldsA, w, lane);
    if (J != I) stage_panel(plane, J, ldsB, w, lane);

    // ---- in-prologue scale compute (former k_scale, op-order identical) ----
    shd[t] = parts1[t];
    __syncthreads();
    for (int off = 128; off; off >>= 1) {
        if (t < off) shd[t] += shd[t + off];
        __syncthreads();
    }
    double S1 = shd[0];
    __syncthreads();
    {
        float c0 = 0.f, c1 = 0.f, c2 = 0.f, c3 = 0.f;
        #pragma unroll 16
        for (int b = 0; b < CONVB; b += 4) {
            c0 += part[(b + 0) * DIM + t];
            c1 += part[(b + 1) * DIM + t];
            c2 += part[(b + 2) * DIM + t];
            c3 += part[(b + 3) * DIM + t];
        }
        double c = (double)((c0 + c1) + (c2 + c3));
        shd[t] = c * c;
    }
    __syncthreads();
    for (int off = 128; off; off >>= 1) {
        if (t < off) shd[t] += shd[t + off];
        __syncthreads();
    }
    double S2    = shd[0];
    double nd    = (double)NROWS;
    double sumL2 = 2.0 * nd * S1 - 2.0 * S2;
    double bw    = sumL2 / (nd * nd - nd) / 4.0;   // / KERNEL_MUL^(KERNEL_NUM//2)
    float  s     = (float)(-1.0 / (16.0 * bw * 0.69314718055994530942));
    f32x2  m2s   = {-2.0f * s, -2.0f * s};

    asm volatile("s_waitcnt vmcnt(0)");
    __syncthreads();

    float wtot = 0.0f;
    int curI = I, curJ = J;
    int pI = 0, pJ = 0;

    f32x4 accA[4][4], accB[4][4];

    // ---- first tile: reads + MFMA into accA (no epilogue partner) ----
    {
        const ulonglong2* lB  = (curJ == curI) ? ldsA : ldsB;
        const ulonglong2* pAl = ldsA + lq * 128 + wr * 64 + lrx;
        const ulonglong2* pBl = lB   + lq * 128 + wc * 64 + lrx;
        #pragma unroll
        for (int tt = 0; tt < 4; ++tt) {
            ulonglong2 fA[4], fB[4];
            #pragma unroll
            for (int m = 0; m < 4; ++m) fA[m] = pAl[tt * 512 + m * 16];
            #pragma unroll
            for (int n = 0; n < 4; ++n) fB[n] = pBl[tt * 512 + n * 16];
            #pragma unroll
            for (int m = 0; m < 4; ++m)
                #pragma unroll
                for (int n = 0; n < 4; ++n) {
                    f32x4 c0 = (tt == 0) ? (f32x4){0.f,0.f,0.f,0.f} : accA[m][n];
                    accA[m][n] = __builtin_amdgcn_mfma_f32_16x16x32_fp8_fp8(
                        (long)fA[m].x, (long)fB[n].x, c0, 0, 0, 0);
                }
            #pragma unroll
            for (int m = 0; m < 4; ++m)
                #pragma unroll
                for (int n = 0; n < 4; ++n)
                    accA[m][n] = __builtin_amdgcn_mfma_f32_16x16x32_fp8_fp8(
                        (long)fA[m].y, (long)fB[n].y, accA[m][n], 0, 0, 0);
        }
        __syncthreads();   // all waves' LDS reads retired
        int nI = curI, nJ = curJ + 1;
        if (nJ == 64) { nI = curI + 1; nJ = nI; }
        if (t0 + 1 < t1) {
            if (nI != curI) stage_panel(plane, nI, ldsA, w, lane);
            else            stage_panel(plane, nJ, ldsB, w, lane);
        }
        pI = curI; pJ = curJ; curI = nI; curJ = nJ;
    }

    // ---- steady state: MFMA(cur)->accB interleaved with epilogue(accA) ----
    #pragma unroll 1
    for (int tile = t0 + 1; tile < t1; ++tile) {
        asm volatile("s_waitcnt vmcnt(0)");
        __syncthreads();                       // cur tile panels in LDS

        const ulonglong2* lB  = (curJ == curI) ? ldsA : ldsB;
        const ulonglong2* pAl = ldsA + lq * 128 + wr * 64 + lrx;
        const ulonglong2* pBl = lB   + lq * 128 + wc * 64 + lrx;

        // prev-tile epilogue constants
        float pwgt = (pJ == pI) ? 1.0f : 2.0f;
        float psgn = ((pI < 32) == (pJ < 32)) ? 1.0f : -1.0f;
        int pro = pI * 128 + wr * 64;
        int pco = pJ * 128 + wc * 64;
        float4 sqa4[4];
        float  psqbv[4];
        #pragma unroll
        for (int m = 0; m < 4; ++m) sqa4[m] = *(const float4*)&sq[pro + m * 16 + lq * 4];
        #pragma unroll
        for (int n = 0; n < 4; ++n) psqbv[n] = s * sq[pco + n * 16 + lr];
        f32x2 pssa01[4], pssa23[4];
        #pragma unroll
        for (int m = 0; m < 4; ++m) {
            pssa01[m] = (f32x2){s * sqa4[m].x, s * sqa4[m].y};
            pssa23[m] = (f32x2){s * sqa4[m].z, s * sqa4[m].w};
        }
        f32x2 eac0 = {0.f, 0.f}, eac1 = {0.f, 0.f};

        #pragma unroll
        for (int tt = 0; tt < 4; ++tt) {
            // 1) cur-tile fragment reads (LDS pipe)
            ulonglong2 fA[4], fB[4];
            #pragma unroll
            for (int m = 0; m < 4; ++m) fA[m] = pAl[tt * 512 + m * 16];
            #pragma unroll
            for (int n = 0; n < 4; ++n) fB[n] = pBl[tt * 512 + n * 16];
            // 2) prev-tile epilogue chunk tt (pure-register VALU; fills lgkm
            //    shadow of the reads above, overlaps MFMA below at pipe level)
            {
                f32x2 sa01 = pssa01[tt], sa23 = pssa23[tt];
                #pragma unroll
                for (int n = 0; n < 4; ++n) {
                    f32x2 sbn = {psqbv[n], psqbv[n]};
                    f32x2 a01 = {accA[tt][n][0], accA[tt][n][1]};
                    f32x2 a23 = {accA[tt][n][2], accA[tt][n][3]};
                    f32x2 e01 = (sa01 + sbn) + m2s * a01;
                    f32x2 e23 = (sa23 + sbn) + m2s * a23;
                    f32x2 u01, u23;
                    u01.x = __builtin_amdgcn_exp2f(e01.x);
                    u01.y = __builtin_amdgcn_exp2f(e01.y);
                    u23.x = __builtin_amdgcn_exp2f(e23.x);
                    u23.y = __builtin_amdgcn_exp2f(e23.y);
                    f32x2 p2a = u01 * u01, p4a = p2a * p2a, p8a = p4a * p4a, p16a = p8a * p8a;
                    f32x2 p2b = u23 * u23, p4b = p2b * p2b, p8b = p4b * p4b, p16b = p8b * p8b;
                    eac0 += ((u01 + p2a) + (p4a + p8a)) + p16a;
                    eac1 += ((u23 + p2b) + (p4b + p8b)) + p16b;
                }
            }
            // 3) cur-tile MFMA group (matrix pipe)
            #pragma unroll
            for (int m = 0; m < 4; ++m)
                #pragma unroll
                for (int n = 0; n < 4; ++n) {
                    f32x4 c0 = (tt == 0) ? (f32x4){0.f,0.f,0.f,0.f} : accB[m][n];
                    accB[m][n] = __builtin_amdgcn_mfma_f32_16x16x32_fp8_fp8(
                        (long)fA[m].x, (long)fB[n].x, c0, 0, 0, 0);
                }
            #pragma unroll
            for (int m = 0; m < 4; ++m)
                #pragma unroll
                for (int n = 0; n < 4; ++n)
                    accB[m][n] = __builtin_amdgcn_mfma_f32_16x16x32_fp8_fp8(
                        (long)fA[m].y, (long)fB[n].y, accB[m][n], 0, 0, 0);
        }
        wtot += ((eac0.x + eac0.y) + (eac1.x + eac1.y)) * psgn * pwgt;

        __syncthreads();                       // all waves' LDS reads retired
        int nI = curI, nJ = curJ + 1;
        if (nJ == 64) { nI = curI + 1; nJ = nI; }
        if (tile + 1 < t1) {
            if (nI != curI) stage_panel(plane, nI, ldsA, w, lane);
            else            stage_panel(plane, nJ, ldsB, w, lane);
        }
        // rotate: accA <- accB (static unrolled copy)
        #pragma unroll
        for (int m = 0; m < 4; ++m)
            #pragma unroll
            for (int n = 0; n < 4; ++n) accA[m][n] = accB[m][n];
        pI = curI; pJ = curJ; curI = nI; curJ = nJ;
    }

    // ---- drain: epilogue of the last tile ----
    {
        float pwgt = (pJ == pI) ? 1.0f : 2.0f;
        float psgn = ((pI < 32) == (pJ < 32)) ? 1.0f : -1.0f;
        int pro = pI * 128 + wr * 64;
        int pco = pJ * 128 + wc * 64;
        float4 sqa4[4];
        float  psqbv[4];
        #pragma unroll
        for (int m = 0; m < 4; ++m) sqa4[m] = *(const float4*)&sq[pro + m * 16 + lq * 4];
        #pragma unroll
        for (int n = 0; n < 4; ++n) psqbv[n] = s * sq[pco + n * 16 + lr];
        f32x2 pssa01[4], pssa23[4];
        #pragma unroll
        for (int m = 0; m < 4; ++m) {
            pssa01[m] = (f32x2){s * sqa4[m].x, s * sqa4[m].y};
            pssa23[m] = (f32x2){s * sqa4[m].z, s * sqa4[m].w};
        }
        f32x2 eac0 = {0.f, 0.f}, eac1 = {0.f, 0.f};
        #pragma unroll
        for (int m = 0; m < 4; ++m) {
            f32x2 sa01 = pssa01[m], sa23 = pssa23[m];
            #pragma unroll
            for (int n = 0; n < 4; ++n) {
                f32x2 sbn = {psqbv[n], psqbv[n]};
                f32x2 a01 = {accA[m][n][0], accA[m][n][1]};
                f32x2 a23 = {accA[m][n][2], accA[m][n][3]};
                f32x2 e01 = (sa01 + sbn) + m2s * a01;
                f32x2 e23 = (sa23 + sbn) + m2s * a23;
                f32x2 u01, u23;
                u01.x = __builtin_amdgcn_exp2f(e01.x);
                u01.y = __builtin_amdgcn_exp2f(e01.y);
                u23.x = __builtin_amdgcn_exp2f(e23.x);
                u23.y = __builtin_amdgcn_exp2f(e23.y);
                f32x2 p2a = u01 * u01, p4a = p2a * p2a, p8a = p4a * p4a, p16a = p8a * p8a;
                f32x2 p2b = u23 * u23, p4b = p2b * p2b, p8b = p4b * p4b, p16b = p8b * p8b;
                eac0 += ((u01 + p2a) + (p4a + p8a)) + p16a;
                eac1 += ((u23 + p2b) + (p4b + p8b)) + p16b;
            }
        }
        wtot += ((eac0.x + eac0.y) + (eac1.x + eac1.y)) * psgn * pwgt;
    }

    #pragma unroll
    for (int off = 32; off; off >>= 1) wtot += __shfl_xor(wtot, off, 64);
    if (lane == 0) wsum[w] = wtot;
    __syncthreads();
    if (t == 0) {
        float tot = (wsum[0] + wsum[1] + wsum[2] + wsum[3])
                  * (1.0f / ((float)HALF * (float)HALF));
        float r = atomicAdd(&outacc[bid & 7], tot);
        asm volatile("" :: "v"(r) : "memory");   // order counter after commit
        unsigned prev = atomicAdd(cnt, 1u);
        if (prev == (unsigned)(GRIDP - 1)) {
            float total = 0.0f;
            #pragma unroll
            for (int k2 = 0; k2 < 8; ++k2) total += atomicAdd(&outacc[k2], 0.0f);
            out[0] = total;
        }
    }
}

extern "C" void kernel_launch(void* const* d_in, const int* in_sizes, int n_in,
                              void* d_out, int out_size, void* d_ws, size_t ws_size,
                              hipStream_t stream) {
    const float* src = (const float*)d_in[0];
    const float* tgt = (const float*)d_in[1];
    float* out = (float*)d_out;

    char* ws = (char*)d_ws;
    unsigned int* cnt = (unsigned int*)(ws + 0);                 // 4 B
    float*  outacc = (float*)(ws + 64);                          // 32 B
    float*  sq     = (float*)(ws + 128);                         // 32768 B
    float*  part   = (float*)(ws + 33024);                       // 256*256*4 B
    double* parts1 = (double*)(ws + 295424);                     // 256*8 B
    unsigned char* hi = (unsigned char*)(ws + 297472);           // 2 MB, 16B-aligned

    k_conv <<<CONVB, 256, 0, stream>>>(src, tgt, hi, sq, part, parts1,
                                       outacc, cnt, out);
    k_pairs<<<GRIDP, 256, 0, stream>>>(hi, sq, part, parts1, outacc, cnt, out);
}